// Round 1
// baseline (95.870 us; speedup 1.0000x reference)
//
#include <hip/hip_runtime.h>

// Problem constants (match reference setup_inputs()).
constexpr int S = 2048;   // N_SAMPLES
constexpr int C = 4096;   // N_CHANNELS
constexpr int K = 4;      // N_COMPONENTS

constexpr int BLOCK = 256;
constexpr int VEC = 4;                 // channels per thread (float4 store)
constexpr int CHUNK = BLOCK * VEC;     // 1024 channels per block
constexpr int CHUNKS_PER_SAMPLE = C / CHUNK;  // 4

// 4-byte-aligned float4: lets the compiler emit a legal wide load for the
// gathered (non-16B-aligned) component window without UB.
typedef float f4u __attribute__((ext_vector_type(4), aligned(4)));

__global__ __launch_bounds__(BLOCK) void smf_kernel(
    const float* __restrict__ comp,      // K x C
    const float* __restrict__ contrib,   // S x K
    const float* __restrict__ shift,     // S x K
    float* __restrict__ out)             // S x C
{
    const int s  = blockIdx.x >> 2;            // CHUNKS_PER_SAMPLE == 4
    const int c0 = (blockIdx.x & 3) * CHUNK;
    const int c  = c0 + (int)threadIdx.x * VEC;

    // Per-sample params: same address across the wave -> broadcast loads.
    float w0[K], w1[K];
    int   m[K];
    int mmin = 1 << 30, mmax = -(1 << 30);
#pragma unroll
    for (int k = 0; k < K; ++k) {
        const float sh = shift[s * K + k];
        const float ct = contrib[s * K + k];
        const float mf = floorf(sh);
        const float f  = sh - mf;
        m[k]  = (int)mf;
        w0[k] = ct * (1.0f - f);
        w1[k] = ct * f;
        mmin = min(mmin, m[k]);
        mmax = max(mmax, m[k]);
    }

    float4 acc = make_float4(0.f, 0.f, 0.f, 0.f);

    // Fast path: every tap index for channels [c, c+3] is in [0, C).
    // Tap indices span [c + mmin, c + 3 + mmax + 1].
    const bool fast = (c + mmin >= 0) && (c + VEC - 1 + mmax + 1 < C);
    if (fast) {
#pragma unroll
        for (int k = 0; k < K; ++k) {
            const float* p = comp + k * C + c + m[k];
            const f4u  v = *(const f4u*)p;    // taps m for the 4 channels
            const float e = p[4];             // 5th value: tap m+1 of channel c+3
            acc.x += w0[k] * v.x + w1[k] * v.y;
            acc.y += w0[k] * v.y + w1[k] * v.z;
            acc.z += w0[k] * v.z + w1[k] * v.w;
            acc.w += w0[k] * v.w + w1[k] * e;
        }
    } else {
        // Edge path (only threads near channel 0 / C): masked scalar taps,
        // exactly the reference semantics.
        float a[VEC] = {0.f, 0.f, 0.f, 0.f};
#pragma unroll
        for (int j = 0; j < VEC; ++j) {
            const int cc = c + j;
#pragma unroll
            for (int k = 0; k < K; ++k) {
                const int i0 = cc + m[k];
                const int i1 = i0 + 1;
                const float g0 = (i0 >= 0 && i0 < C) ? comp[k * C + i0] : 0.f;
                const float g1 = (i1 >= 0 && i1 < C) ? comp[k * C + i1] : 0.f;
                a[j] += w0[k] * g0 + w1[k] * g1;
            }
        }
        acc = make_float4(a[0], a[1], a[2], a[3]);
    }

    // c is a multiple of 4 -> 16B-aligned coalesced store.
    *(float4*)(out + s * C + c) = acc;
}

extern "C" void kernel_launch(void* const* d_in, const int* in_sizes, int n_in,
                              void* d_out, int out_size, void* d_ws, size_t ws_size,
                              hipStream_t stream) {
    // d_in[0] = inputs (S x C)  -- UNUSED by the math (shape only), never read.
    const float* comp    = (const float*)d_in[1];  // K x C
    const float* contrib = (const float*)d_in[2];  // S x K
    const float* shift   = (const float*)d_in[3];  // S x K
    float* out = (float*)d_out;                    // S x C

    const int grid = S * CHUNKS_PER_SAMPLE;        // 8192 blocks
    smf_kernel<<<grid, BLOCK, 0, stream>>>(comp, contrib, shift, out);
}